// Round 7
// baseline (164.284 us; speedup 1.0000x reference)
//
#include <hip/hip_runtime.h>
#include <hip/hip_bf16.h>

// Problem constants (fixed by the reference).
#define BB 32
#define CC 32
#define PP 4096      // H*W
#define KS 9
#define KK 64        // output channels
#define CK 288       // C*KS

typedef __attribute__((ext_vector_type(8))) short short8;
typedef __attribute__((ext_vector_type(4))) float float4v;
typedef __attribute__((ext_vector_type(4))) int int4v;

__device__ inline unsigned short f2bf(float f) {
    __hip_bfloat16 h = __float2bfloat16(f);
    return __builtin_bit_cast(unsigned short, h);
}

// ---- prep (merged): blocks [0,512) transpose x -> xt bf16 pixel-major
//      (1 pixel/thread, coalesced 256B/wave scalar loads, 64B row stores);
//      blocks [512,584) swizzle W -> wa bf16 in MFMA A-fragment order.
// A-frag flat: i = ((kc*4 + mt)*64 + lane)*8 + j
//   -> A[m=ko=mt*16+(lane&15)][k'=kc*32+(lane>>4)*8+j], W-elem = w[ko][c*9+kc], c=(lane>>4)*8+j
__global__ __launch_bounds__(256)
void prep_kernel(const float* __restrict__ x, const float* __restrict__ w,
                 unsigned short* __restrict__ xt, unsigned short* __restrict__ wa) {
    const int t = threadIdx.x;
    const int blk = blockIdx.x;
    if (blk < 512) {
        const int b = blk >> 4;
        const int p = ((blk & 15) << 8) + t;
        const float* xb = x + (size_t)b * CC * PP + p;
        unsigned int buf[16];
#pragma unroll
        for (int c2 = 0; c2 < 16; ++c2) {
            float lo = xb[(size_t)(2 * c2) * PP];
            float hi = xb[(size_t)(2 * c2 + 1) * PP];
            buf[c2] = (unsigned int)f2bf(lo) | ((unsigned int)f2bf(hi) << 16);
        }
        uint4* dst = (uint4*)(xt + ((size_t)b * PP + p) * CC);
        const uint4* s = (const uint4*)buf;
#pragma unroll
        for (int j = 0; j < 4; ++j) dst[j] = s[j];
    } else {
        int i = (blk - 512) * 256 + t;
        if (i < KK * CK) {
            int j  = i & 7;
            int l  = (i >> 3) & 63;
            int mt = (i >> 9) & 3;
            int kc = i >> 11;                 // = neighbor k
            int c  = ((l >> 4) << 3) + j;
            int ko = (mt << 4) + (l & 15);
            wa[i] = f2bf(w[ko * CK + c * KS + kc]);
        }
    }
}

// ---- main v4 body, ATTRIBUTION PROBE build: internal x10 repeat.
// Each rep is an idempotent recompute+rewrite of the same out values.
// asm memory clobber per rep defeats LICM/DSE (all params __restrict__).
// warm-main cost/pass = (dur_us - 85.99) / 9. If >= ~4.4us/pass this
// dispatch exceeds the ~44us poison fills and lands in top-5 WITH COUNTERS.
__global__ __launch_bounds__(256, 4)
void abc_mfma4_r10_kernel(const unsigned short* __restrict__ xt,
                          const unsigned short* __restrict__ wa,
                          const int* __restrict__ idx,
                          float* __restrict__ out) {
    __shared__ unsigned short was[KK * CK];          // 36864 B
    const int t    = threadIdx.x;
    const int l    = t & 63;
    const int w    = t >> 6;
    const int blk  = blockIdx.x;
    const int b    = ((blk & 7) << 2) | ((blk >> 3) & 3);
    const int tile = blk >> 5;                               // 0..31
    const int p0   = (tile << 7) + (w << 5);                 // wave's 32 pixels
    const int lo16 = l & 15;
    const int quad = l >> 4;

    // stage wa -> LDS (2304 uint4, 9 per thread, coalesced) — once
    {
        const uint4* s = (const uint4*)wa;
        uint4* d = (uint4*)was;
#pragma unroll
        for (int j = 0; j < 9; ++j) d[t + 256 * j] = s[t + 256 * j];
    }

    const unsigned short* xtb = xt + (size_t)b * PP * CC;

    // gather-lane role: pixel gpix = l>>2 (within nt half), chunk l&3
    const int gpix   = l >> 2;
    const int gchunk = l & 3;
    int q[2][KS];
#pragma unroll
    for (int nt = 0; nt < 2; ++nt) {
        const int pl = p0 + nt * 16 + gpix;
#pragma unroll
        for (int kc = 0; kc < KS; ++kc) q[nt][kc] = idx[pl * KS + kc];
    }

    // bpermute source byte-addr: fragment lane l pulls from lane 4*(l&15)+(l>>4)
    const int src4 = (((lo16 << 2) | quad) << 2);

    __syncthreads();

#pragma unroll 1
    for (int rep = 0; rep < 10; ++rep) {
        asm volatile("" ::: "memory");   // forbid LICM of loads / DSE of stores

        float4v acc[8];   // [mt][nt] -> acc[mt*2+nt]
#pragma unroll
        for (int i = 0; i < 8; ++i) acc[i] = (float4v){0.f, 0.f, 0.f, 0.f};

        // 3-deep register pipeline over kc (full unroll -> static indexing)
        int4v g[3][2];
#pragma unroll
        for (int kk = 0; kk < 2; ++kk)
#pragma unroll
            for (int nt = 0; nt < 2; ++nt)
                g[kk][nt] = *(const int4v*)(xtb + (size_t)q[nt][kk] * CC + (gchunk << 3));

#pragma unroll
        for (int kc = 0; kc < KS; ++kc) {
            if (kc + 2 < KS) {
                const int nb = (kc + 2) % 3;
#pragma unroll
                for (int nt = 0; nt < 2; ++nt)
                    g[nb][nt] = *(const int4v*)(xtb + (size_t)q[nt][kc + 2] * CC + (gchunk << 3));
            }
            const int cb = kc % 3;
            short8 bf[2];
#pragma unroll
            for (int nt = 0; nt < 2; ++nt) {
                int4v r;
#pragma unroll
                for (int j = 0; j < 4; ++j)
                    r[j] = __builtin_amdgcn_ds_bpermute(src4, g[cb][nt][j]);
                bf[nt] = __builtin_bit_cast(short8, r);
            }
#pragma unroll
            for (int mt = 0; mt < 4; ++mt) {
                const short8 a = *(const short8*)(was + ((size_t)(kc * 4 + mt) * 64 + l) * 8);
#pragma unroll
                for (int nt = 0; nt < 2; ++nt)
                    acc[mt * 2 + nt] =
                        __builtin_amdgcn_mfma_f32_16x16x32_bf16(a, bf[nt], acc[mt * 2 + nt], 0, 0, 0);
            }
        }

        // D layout: m(ko_sub)=quad*4+r, n(pixel)=lo16.
        float* ob = out + (size_t)b * KK * PP + p0 + lo16;
#pragma unroll
        for (int mt = 0; mt < 4; ++mt) {
            float* om = ob + (size_t)(mt * 16 + quad * 4) * PP;
#pragma unroll
            for (int r = 0; r < 4; ++r)
#pragma unroll
                for (int nt = 0; nt < 2; ++nt)
                    __builtin_nontemporal_store(acc[mt * 2 + nt][r],
                                                om + (size_t)r * PP + nt * 16);
        }
    }
}

// ---- fallback (ws too small): round-2 VALU kernel ----
__global__ __launch_bounds__(256)
void abc_valu_kernel(const float* __restrict__ x, const float* __restrict__ w,
                     const int* __restrict__ idx, float* __restrict__ out) {
    __shared__ float xrow[PP];
    const int t = threadIdx.x;
    const int b = blockIdx.x >> 4;
    const int p = ((blockIdx.x & 15) << 8) + t;
    int q[KS];
#pragma unroll
    for (int k = 0; k < KS; ++k) q[k] = idx[p * KS + k];
    float acc[KK];
#pragma unroll
    for (int i = 0; i < KK; ++i) acc[i] = 0.0f;
    const float* xb = x + (size_t)b * CC * PP;
#pragma unroll 1
    for (int c = 0; c < CC; ++c) {
        const float4* src = (const float4*)(xb + (size_t)c * PP);
        float4* dst = (float4*)xrow;
#pragma unroll
        for (int j = 0; j < 4; ++j) dst[j * 256 + t] = src[j * 256 + t];
        __syncthreads();
        float xv[KS];
#pragma unroll
        for (int k = 0; k < KS; ++k) xv[k] = xrow[q[k]];
#pragma unroll
        for (int k = 0; k < KS; ++k) {
            const int col = c * KS + k;
#pragma unroll
            for (int ko = 0; ko < KK; ++ko)
                acc[ko] += xv[k] * w[ko * CK + col];
        }
        __syncthreads();
    }
    float* ob = out + (size_t)b * KK * PP + p;
#pragma unroll
    for (int ko = 0; ko < KK; ++ko)
        ob[(size_t)ko * PP] = acc[ko];
}

extern "C" void kernel_launch(void* const* d_in, const int* in_sizes, int n_in,
                              void* d_out, int out_size, void* d_ws, size_t ws_size,
                              hipStream_t stream) {
    const float* x  = (const float*)d_in[0];
    const float* w  = (const float*)d_in[1];
    const int* idx  = (const int*)d_in[2];
    float* out      = (float*)d_out;

    const size_t xt_bytes = (size_t)BB * PP * CC * 2;    // 8,388,608
    const size_t need     = xt_bytes + (size_t)KK * CK * 2;

    if (ws_size >= need) {
        unsigned short* xt = (unsigned short*)d_ws;
        unsigned short* wa = (unsigned short*)((char*)d_ws + xt_bytes);
        const int wb_blocks = (KK * CK + 255) / 256;     // 72
        prep_kernel<<<512 + wb_blocks, 256, 0, stream>>>(x, w, xt, wa);
        abc_mfma4_r10_kernel<<<BB * (PP / 128), 256, 0, stream>>>(xt, wa, idx, out);
    } else {
        abc_valu_kernel<<<BB * (PP / 256), 256, 0, stream>>>(x, w, idx, out);
    }
}

// Round 8
// 87.207 us; speedup vs baseline: 1.8838x; 1.8838x over previous
//
#include <hip/hip_runtime.h>
#include <hip/hip_bf16.h>

// Problem constants (fixed by the reference).
#define BB 32
#define CC 32
#define PP 4096      // H*W
#define KS 9
#define KK 64        // output channels
#define CK 288       // C*KS

typedef __attribute__((ext_vector_type(8))) short short8;
typedef __attribute__((ext_vector_type(4))) float float4v;
typedef __attribute__((ext_vector_type(4))) int int4v;

__device__ inline unsigned short f2bf(float f) {
    __hip_bfloat16 h = __float2bfloat16(f);
    return __builtin_bit_cast(unsigned short, h);
}

// ---- prep (merged): blocks [0,512) transpose x -> xt bf16 pixel-major
//      (1 pixel/thread, coalesced 256B/wave scalar loads, 64B row stores);
//      blocks [512,584) swizzle W -> wa bf16 in MFMA A-fragment order.
// A-frag flat: i = ((kc*4 + mt)*64 + lane)*8 + j
//   -> A[m=ko=mt*16+(lane&15)][k'=kc*32+(lane>>4)*8+j], W-elem = w[ko][c*9+kc], c=(lane>>4)*8+j
__global__ __launch_bounds__(256)
void prep_kernel(const float* __restrict__ x, const float* __restrict__ w,
                 unsigned short* __restrict__ xt, unsigned short* __restrict__ wa) {
    const int t = threadIdx.x;
    const int blk = blockIdx.x;
    if (blk < 512) {
        const int b = blk >> 4;
        const int p = ((blk & 15) << 8) + t;
        const float* xb = x + (size_t)b * CC * PP + p;
        unsigned int buf[16];
#pragma unroll
        for (int c2 = 0; c2 < 16; ++c2) {
            float lo = xb[(size_t)(2 * c2) * PP];
            float hi = xb[(size_t)(2 * c2 + 1) * PP];
            buf[c2] = (unsigned int)f2bf(lo) | ((unsigned int)f2bf(hi) << 16);
        }
        uint4* dst = (uint4*)(xt + ((size_t)b * PP + p) * CC);
        const uint4* s = (const uint4*)buf;
#pragma unroll
        for (int j = 0; j < 4; ++j) dst[j] = s[j];
    } else {
        int i = (blk - 512) * 256 + t;
        if (i < KK * CK) {
            int j  = i & 7;
            int l  = (i >> 3) & 63;
            int mt = (i >> 9) & 3;
            int kc = i >> 11;                 // = neighbor k
            int c  = ((l >> 4) << 3) + j;
            int ko = (mt << 4) + (l & 15);
            wa[i] = f2bf(w[ko * CK + c * KS + kc]);
        }
    }
}

// ---- main v6: v4 + FULL-DEPTH gather issue. Round-7 probe attribution:
// warm main 8.7us, cold main ~22us (13us cold-miss stall; FETCH shows xt/idx
// come from HBM once then stay cached; MfmaUtil 19% / VALUBusy 6% -> latency-
// bound). v4's 3-deep pipeline held only ~6 of 18 gathers in flight against
// ~900cy misses. Here ALL 18 gathers issue before the wa-staging barrier;
// the barrier's vmcnt(0) drain overlaps them all in one latency window.
// VGPR ~140 -> __launch_bounds__(256,3); occupancy stays 12 waves/CU
// (= measured 37.5%). Stores stay nontemporal: L2-allocating the 33.5MB out
// stream would thrash the ~1MB/XCD xt working set (FETCH-verified resident).
__global__ __launch_bounds__(256, 3)
void abc_mfma6_kernel(const unsigned short* __restrict__ xt,
                      const unsigned short* __restrict__ wa,
                      const int* __restrict__ idx,
                      float* __restrict__ out) {
    __shared__ unsigned short was[KK * CK];          // 36864 B
    const int t    = threadIdx.x;
    const int l    = t & 63;
    const int w    = t >> 6;
    const int blk  = blockIdx.x;
    const int b    = ((blk & 7) << 2) | ((blk >> 3) & 3);
    const int tile = blk >> 5;                               // 0..31
    const int p0   = (tile << 7) + (w << 5);                 // wave's 32 pixels
    const int lo16 = l & 15;
    const int quad = l >> 4;

    // stage wa -> LDS (2304 uint4, 9 per thread, coalesced)
    {
        const uint4* s = (const uint4*)wa;
        uint4* d = (uint4*)was;
#pragma unroll
        for (int j = 0; j < 9; ++j) d[t + 256 * j] = s[t + 256 * j];
    }

    const unsigned short* xtb = xt + (size_t)b * PP * CC;

    // gather-lane role: pixel gpix = l>>2 (within nt half), chunk l&3
    const int gpix   = l >> 2;
    const int gchunk = l & 3;
    int q[2][KS];
#pragma unroll
    for (int nt = 0; nt < 2; ++nt) {
        const int pl = p0 + nt * 16 + gpix;
#pragma unroll
        for (int kc = 0; kc < KS; ++kc) q[nt][kc] = idx[pl * KS + kc];
    }

    // issue ALL 18 gathers up-front (72 VGPRs of buffers, max MLP);
    // the syncthreads below drains vmcnt once for the whole batch.
    int4v g[KS][2];
#pragma unroll
    for (int kc = 0; kc < KS; ++kc)
#pragma unroll
        for (int nt = 0; nt < 2; ++nt)
            g[kc][nt] = *(const int4v*)(xtb + (size_t)q[nt][kc] * CC + (gchunk << 3));

    // bpermute source byte-addr: fragment lane l pulls from lane 4*(l&15)+(l>>4)
    const int src4 = (((lo16 << 2) | quad) << 2);

    float4v acc[8];   // [mt][nt] -> acc[mt*2+nt]
#pragma unroll
    for (int i = 0; i < 8; ++i) acc[i] = (float4v){0.f, 0.f, 0.f, 0.f};

    __syncthreads();

#pragma unroll
    for (int kc = 0; kc < KS; ++kc) {
        // redistribute gather buffer kc into MFMA B-fragment order
        short8 bf[2];
#pragma unroll
        for (int nt = 0; nt < 2; ++nt) {
            int4v r;
#pragma unroll
            for (int j = 0; j < 4; ++j)
                r[j] = __builtin_amdgcn_ds_bpermute(src4, g[kc][nt][j]);
            bf[nt] = __builtin_bit_cast(short8, r);
        }
#pragma unroll
        for (int mt = 0; mt < 4; ++mt) {
            const short8 a = *(const short8*)(was + ((size_t)(kc * 4 + mt) * 64 + l) * 8);
#pragma unroll
            for (int nt = 0; nt < 2; ++nt)
                acc[mt * 2 + nt] =
                    __builtin_amdgcn_mfma_f32_16x16x32_bf16(a, bf[nt], acc[mt * 2 + nt], 0, 0, 0);
        }
    }

    // D layout: m(ko_sub)=quad*4+r, n(pixel)=lo16. Nontemporal stores (keep:
    // avoids L2-allocating the out stream over the xt gather working set).
    float* ob = out + (size_t)b * KK * PP + p0 + lo16;
#pragma unroll
    for (int mt = 0; mt < 4; ++mt) {
        float* om = ob + (size_t)(mt * 16 + quad * 4) * PP;
#pragma unroll
        for (int r = 0; r < 4; ++r)
#pragma unroll
            for (int nt = 0; nt < 2; ++nt)
                __builtin_nontemporal_store(acc[mt * 2 + nt][r],
                                            om + (size_t)r * PP + nt * 16);
    }
}

// ---- fallback (ws too small): round-2 VALU kernel ----
__global__ __launch_bounds__(256)
void abc_valu_kernel(const float* __restrict__ x, const float* __restrict__ w,
                     const int* __restrict__ idx, float* __restrict__ out) {
    __shared__ float xrow[PP];
    const int t = threadIdx.x;
    const int b = blockIdx.x >> 4;
    const int p = ((blockIdx.x & 15) << 8) + t;
    int q[KS];
#pragma unroll
    for (int k = 0; k < KS; ++k) q[k] = idx[p * KS + k];
    float acc[KK];
#pragma unroll
    for (int i = 0; i < KK; ++i) acc[i] = 0.0f;
    const float* xb = x + (size_t)b * CC * PP;
#pragma unroll 1
    for (int c = 0; c < CC; ++c) {
        const float4* src = (const float4*)(xb + (size_t)c * PP);
        float4* dst = (float4*)xrow;
#pragma unroll
        for (int j = 0; j < 4; ++j) dst[j * 256 + t] = src[j * 256 + t];
        __syncthreads();
        float xv[KS];
#pragma unroll
        for (int k = 0; k < KS; ++k) xv[k] = xrow[q[k]];
#pragma unroll
        for (int k = 0; k < KS; ++k) {
            const int col = c * KS + k;
#pragma unroll
            for (int ko = 0; ko < KK; ++ko)
                acc[ko] += xv[k] * w[ko * CK + col];
        }
        __syncthreads();
    }
    float* ob = out + (size_t)b * KK * PP + p;
#pragma unroll
    for (int ko = 0; ko < KK; ++ko)
        ob[(size_t)ko * PP] = acc[ko];
}

extern "C" void kernel_launch(void* const* d_in, const int* in_sizes, int n_in,
                              void* d_out, int out_size, void* d_ws, size_t ws_size,
                              hipStream_t stream) {
    const float* x  = (const float*)d_in[0];
    const float* w  = (const float*)d_in[1];
    const int* idx  = (const int*)d_in[2];
    float* out      = (float*)d_out;

    const size_t xt_bytes = (size_t)BB * PP * CC * 2;    // 8,388,608
    const size_t need     = xt_bytes + (size_t)KK * CK * 2;

    if (ws_size >= need) {
        unsigned short* xt = (unsigned short*)d_ws;
        unsigned short* wa = (unsigned short*)((char*)d_ws + xt_bytes);
        const int wb_blocks = (KK * CK + 255) / 256;     // 72
        prep_kernel<<<512 + wb_blocks, 256, 0, stream>>>(x, w, xt, wa);
        abc_mfma6_kernel<<<BB * (PP / 128), 256, 0, stream>>>(xt, wa, idx, out);
    } else {
        abc_valu_kernel<<<BB * (PP / 256), 256, 0, stream>>>(x, w, idx, out);
    }
}

// Round 9
// 86.978 us; speedup vs baseline: 1.8888x; 1.0026x over previous
//
#include <hip/hip_runtime.h>
#include <hip/hip_bf16.h>

// Problem constants (fixed by the reference).
#define BB 32
#define CC 32
#define PP 4096      // H*W
#define KS 9
#define KK 64        // output channels
#define CK 288       // C*KS

typedef __attribute__((ext_vector_type(8))) short short8;
typedef __attribute__((ext_vector_type(4))) int int4v;
typedef __attribute__((ext_vector_type(16))) float f32x16;

__device__ inline unsigned short f2bf(float f) {
    __hip_bfloat16 h = __float2bfloat16(f);
    return __builtin_bit_cast(unsigned short, h);
}

// ---- fused single-kernel v7: prep eliminated; gather served from LDS.
// Round-8 attribution: main's 22us cold cost = HBM random-64B gather of
// poison-evicted xt (TLP already saturates the miss queue -> un-hideable).
// Fix the memory plan: each block stages x[b][c-half][all 4096 px] as bf16
// into LDS (c2-pair sections, +4-dword skew so gather banks spread), builds
// its own A-fragments from w into LDS, gathers from LDS, accumulates both
// c-halves in VGPR acc. 32x32x16 fragment/D maps reused verbatim from the
// harness-verified v5 (half plays kh's role). Blocks: 1024 thr = 16 waves
// x 32 px = 512 px; 8 blocks per b; grid 256 = 1 block/CU.
// XCD swizzle: blk%8 = dispatch XCD; b = (blk&7)*4+((blk>>3)&3) puts all 8
// blocks of one b on one XCD -> its 0.5MB x-slice L2-resident for staging.
// LDS: xs 8*4100 u32 = 131200 B (+skew), wah 9216 u16 = 18432 B -> 149632 B.
__global__ __launch_bounds__(1024)
void abc_fused_kernel(const float* __restrict__ x, const float* __restrict__ w,
                      const int* __restrict__ idx, float* __restrict__ out) {
    __shared__ unsigned int   xs4[8 * 4100];   // [c2][4096+4pad] u32 = 2 ch bf16
    __shared__ unsigned short wah[9 * 2 * 64 * 8]; // A-frags, one c-half at a time

    const int t     = threadIdx.x;
    const int l     = t & 63;
    const int wv    = t >> 6;                       // wave 0..15
    const int blk   = blockIdx.x;
    const int b     = ((blk & 7) << 2) | ((blk >> 3) & 3);
    const int pb    = blk >> 5;                     // 0..7 pixel block
    const int p0    = pb * 512 + wv * 32;           // wave's 32 pixels
    const int gpix  = l & 31;                       // lane's pixel (B-frag n)
    const int ghalf = l >> 5;                       // k-subgroup (B-frag k-high)

    // neighbor indices for this lane's pixel (lanes l and l+32 duplicate: cheap)
    int q[KS];
    {
        const int* ip = idx + (size_t)(p0 + gpix) * KS;
#pragma unroll
        for (int kc = 0; kc < KS; ++kc) q[kc] = ip[kc];
    }

    f32x16 acc[2];
#pragma unroll
    for (int i = 0; i < 16; ++i) { acc[0][i] = 0.f; acc[1][i] = 0.f; }

    const float* xb0 = x + (size_t)b * CC * PP;

#pragma unroll
    for (int half = 0; half < 2; ++half) {
        if (half) __syncthreads();   // drain half-0 readers before overwrite

        // ---- stage x[b][half*16 .. +16][*] -> xs (bf16 pairs), coalesced.
        // ds_write_b128 is linear (lane t -> bytes 16t within each section):
        // conflict-free, 128 KB per half at LDS peak.
        const float* xh = xb0 + (size_t)(half * 16) * PP;
#pragma unroll
        for (int c2 = 0; c2 < 8; ++c2) {
            const float4 lo = *(const float4*)(xh + (size_t)(2 * c2) * PP + 4 * t);
            const float4 hi = *(const float4*)(xh + (size_t)(2 * c2 + 1) * PP + 4 * t);
            uint4 v;
            v.x = (unsigned)f2bf(lo.x) | ((unsigned)f2bf(hi.x) << 16);
            v.y = (unsigned)f2bf(lo.y) | ((unsigned)f2bf(hi.y) << 16);
            v.z = (unsigned)f2bf(lo.z) | ((unsigned)f2bf(hi.z) << 16);
            v.w = (unsigned)f2bf(lo.w) | ((unsigned)f2bf(hi.w) << 16);
            *(uint4*)(&xs4[c2 * 4100 + 4 * t]) = v;
        }

        // ---- build A-fragments for this c-half: wah[((kc*2+mt)*64+l)*8+j] =
        // w[ko=mt*32+(l&31)][c=(half*16+(l>>5)*8+j)*9 ... ] (v5-verified map).
#pragma unroll
        for (int i = 0; i < 9; ++i) {
            const int wi = t + (i << 10);           // 0..9215
            const int j  = wi & 7;
            const int ll = (wi >> 3) & 63;
            const int mt = (wi >> 9) & 1;
            const int kc = wi >> 10;
            const int ko = (mt << 5) + (ll & 31);
            const int c  = (half << 4) + ((ll >> 5) << 3) + j;
            wah[wi] = f2bf(w[ko * CK + c * KS + kc]);
        }

        __syncthreads();

        // ---- gather from LDS + MFMA. B-frag (n=gpix, k=ghalf*8+j) = 4 u32
        // section reads; section skew (4100) spreads banks: bank=(4*sec+q)%32.
#pragma unroll
        for (int kc = 0; kc < KS; ++kc) {
            int4v r;
#pragma unroll
            for (int jj = 0; jj < 4; ++jj)
                r[jj] = (int)xs4[(ghalf * 4 + jj) * 4100 + q[kc]];
            const short8 bf = __builtin_bit_cast(short8, r);
#pragma unroll
            for (int mt = 0; mt < 2; ++mt) {
                const short8 a = *(const short8*)&wah[(((kc << 1) + mt) * 64 + l) * 8];
                acc[mt] = __builtin_amdgcn_mfma_f32_32x32x16_bf16(a, bf, acc[mt], 0, 0, 0);
            }
        }
    }

    // ---- epilogue (v5-verified D map): row=(r&3)+8*(r>>2)+4*ghalf+32*mt,
    // col=gpix -> lanes 0-31 and 32-63 each cover a full 128B line per store.
    float* ob = out + (size_t)b * KK * PP + p0 + gpix;
#pragma unroll
    for (int mt = 0; mt < 2; ++mt)
#pragma unroll
        for (int r = 0; r < 16; ++r) {
            const int row = (mt << 5) + (r & 3) + ((r >> 2) << 3) + (ghalf << 2);
            __builtin_nontemporal_store(acc[mt][r], ob + (size_t)row * PP);
        }
}

extern "C" void kernel_launch(void* const* d_in, const int* in_sizes, int n_in,
                              void* d_out, int out_size, void* d_ws, size_t ws_size,
                              hipStream_t stream) {
    const float* x  = (const float*)d_in[0];
    const float* w  = (const float*)d_in[1];
    const int* idx  = (const int*)d_in[2];
    float* out      = (float*)d_out;
    (void)d_ws; (void)ws_size;

    // 256 blocks (= BB * PP/512), 1024 threads; no workspace, single launch.
    abc_fused_kernel<<<256, 1024, 0, stream>>>(x, w, idx, out);
}